// Round 1
// baseline (577.899 us; speedup 1.0000x reference)
//
#include <hip/hip_runtime.h>

// Householder reflection, row-wise over [B=16384, L=4096] fp32:
//   out[b, :] = z[b, :] - 2 * v[b, :] * (v[b]·z[b]) / (v[b]·v[b])
//
// HBM-bound: 768 MiB min traffic -> ~128 us at 6.3 TB/s achievable.
//
// R1: wave-per-row rewrite. Previous block-per-row kernel compiled to 32 VGPRs,
// proving the compiler rematerialized (re-read) v/z after the barrier instead of
// holding them in registers; the load->vmcnt(0)->barrier->re-load->store chain
// left HBM at 45% of achievable. Here one wave64 owns one full row:
//   - 16 float4 per lane of v AND z held in registers (~128 data VGPRs,
//     __launch_bounds__(256,1) grants the budget)
//   - 32 independent dwordx4 loads in flight per wave (32 KB MLP -- far above
//     the ~9 KB/CU needed to cover ~900cy HBM latency at 10.3 B/cy/CU)
//   - shuffle-only 64-lane butterfly reduction: no LDS, no __syncthreads
//   - non-temporal stores: dead 'out' stream doesn't evict v/z from L3
// Occupancy drops to ~3 waves/SIMD by design; intra-wave MLP replaces TLP.

#define L 4096
#define WAVES_PER_BLOCK 4
#define BLOCK (WAVES_PER_BLOCK * 64)
#define F4 (L / (64 * 4))  // 16 float4 per lane

typedef float f32x4 __attribute__((ext_vector_type(4)));

__global__ __launch_bounds__(BLOCK, 1) void hh_kernel(
    const float* __restrict__ v,
    const float* __restrict__ z,
    float* __restrict__ out)
{
    const int wave = threadIdx.x >> 6;
    const int lane = threadIdx.x & 63;
    const long long row  = (long long)blockIdx.x * WAVES_PER_BLOCK + wave;
    const long long base = row * (long long)L;

    const f32x4* v4 = reinterpret_cast<const f32x4*>(v + base);
    const f32x4* z4 = reinterpret_cast<const f32x4*>(z + base);
    f32x4*       o4 = reinterpret_cast<f32x4*>(out + base);

    f32x4 vr[F4];
    f32x4 zr[F4];

    // Issue all 32 loads back-to-back: maximal per-wave MLP, one HBM read of
    // each input, fully coalesced (lane j -> 16B at lane stride).
#pragma unroll
    for (int i = 0; i < F4; ++i) {
        vr[i] = v4[lane + i * 64];
        zr[i] = z4[lane + i * 64];
    }

    // Vector accumulators -> 2 FMA chains, horizontal sum at the end.
    f32x4 dotv = {0.f, 0.f, 0.f, 0.f};
    f32x4 nsqv = {0.f, 0.f, 0.f, 0.f};
#pragma unroll
    for (int i = 0; i < F4; ++i) {
        dotv += vr[i] * zr[i];
        nsqv += vr[i] * vr[i];
    }
    float dot = dotv.x + dotv.y + dotv.z + dotv.w;
    float nsq = nsqv.x + nsqv.y + nsqv.z + nsqv.w;

    // 64-lane butterfly: no LDS, no barriers.
#pragma unroll
    for (int off = 32; off > 0; off >>= 1) {
        dot += __shfl_xor(dot, off, 64);
        nsq += __shfl_xor(nsq, off, 64);
    }

    const float s = -2.0f * dot / nsq;

#pragma unroll
    for (int i = 0; i < F4; ++i) {
        f32x4 o = zr[i] + s * vr[i];
        __builtin_nontemporal_store(o, &o4[lane + i * 64]);
    }
}

extern "C" void kernel_launch(void* const* d_in, const int* in_sizes, int n_in,
                              void* d_out, int out_size, void* d_ws, size_t ws_size,
                              hipStream_t stream) {
    const float* v = (const float*)d_in[0];
    const float* z = (const float*)d_in[1];
    float* out = (float*)d_out;

    const int B = in_sizes[0] / L;  // 16384 rows
    hh_kernel<<<B / WAVES_PER_BLOCK, BLOCK, 0, stream>>>(v, z, out);
}